// Round 18
// baseline (148.669 us; speedup 1.0000x reference)
//
#include <hip/hip_runtime.h>
#include <stdint.h>

#define T_ 2048
#define BB_ 4

typedef __bf16 bf16x8 __attribute__((ext_vector_type(8)));
typedef float f32x4 __attribute__((ext_vector_type(4)));
typedef unsigned short u16x8 __attribute__((ext_vector_type(8)));
typedef unsigned int u32x2 __attribute__((ext_vector_type(2)));
typedef unsigned int u32x4 __attribute__((ext_vector_type(4)));

__device__ __forceinline__ unsigned short f2b(float f) {
    unsigned int u = __builtin_bit_cast(unsigned int, f);
    return (unsigned short)((u + 0x7fffu + ((u >> 16) & 1u)) >> 16);
}

__device__ __forceinline__ unsigned cvt_pk(float lo, float hi) {
    unsigned r;
    asm("v_cvt_pk_bf16_f32 %0, %1, %2" : "=v"(r) : "v"(lo), "v"(hi));
    return r;
}

__device__ __forceinline__ void gload16(const void* g, const void* lds) {
    __builtin_amdgcn_global_load_lds(
        (__attribute__((address_space(1))) void*)(uintptr_t)g,
        (__attribute__((address_space(3))) void*)(uintptr_t)(unsigned int)(uintptr_t)lds,
        16, 0, 0);
}

__device__ __forceinline__ bf16x8 ld_b8(const unsigned short* p) {
    return *(const bf16x8*)p;
}

#define MFMA16(a, b, c) __builtin_amdgcn_mfma_f32_16x16x32_bf16((a), (b), (c), 0, 0, 0)
#define SB() __builtin_amdgcn_sched_barrier(0)

// ---------------- merged prep: x->bf16 + both weight transposes -----------
__device__ __forceinline__ void cvtT_body(const float* __restrict__ W,
                                          unsigned short* __restrict__ WT, int K,
                                          int N, int bid, int tid,
                                          unsigned short (*t_)[72]) {
    const int nt = bid % (N / 64), kt = bid / (N / 64);
    const int r = tid >> 2, c = (tid & 3) * 16;
    const float* src = W + (size_t)(kt * 64 + r) * N + nt * 64 + c;
#pragma unroll
    for (int j = 0; j < 16; j += 4) {
        float4 v = *(const float4*)(src + j);
        t_[r][c + j + 0] = f2b(v.x);
        t_[r][c + j + 1] = f2b(v.y);
        t_[r][c + j + 2] = f2b(v.z);
        t_[r][c + j + 3] = f2b(v.w);
    }
    __syncthreads();
    unsigned short* dst = WT + (size_t)(nt * 64 + r) * K + kt * 64 + c;
#pragma unroll
    for (int j = 0; j < 16; ++j) dst[j] = t_[c + j][r];
}

__global__ __launch_bounds__(256) void k_prep(
    const float* __restrict__ x, const float* __restrict__ Wqkv,
    const float* __restrict__ Wout, unsigned short* __restrict__ xb,
    unsigned short* __restrict__ wqkvT, unsigned short* __restrict__ woutT) {
    __shared__ unsigned short t_[64][72];
    const int bid = blockIdx.x, tid = threadIdx.x;
    if (bid < 768) {
        cvtT_body(Wqkv, wqkvT, 1024, 3072, bid, tid, t_);
    } else if (bid < 1024) {
        cvtT_body(Wout, woutT, 1024, 1024, bid - 768, tid, t_);
    } else {
        int i = ((bid - 1024) * 256 + tid) * 4;
        const int stride = 2048 * 256 * 4;
        for (; i < BB_ * T_ * 1024; i += stride) {
            const float4 v = *(const float4*)(x + i);
            *(ushort4*)(xb + i) = make_ushort4(f2b(v.x), f2b(v.y), f2b(v.z), f2b(v.w));
        }
    }
}

// ---------------- 128x192 BK=32 8-wave GEMM, 3-buffer, 2 blocks/CU ---------
// Tail-free grid: 64 x 16 = 1024 blocks = exactly two full 2-per-CU bursts
// (vs 768 blocks = 1.5 bursts costing 2 full burst times). LDS 60 KB.
// Paired-row layout + XOR swizzle (round-15 proven, 0-conflict). 3-buffer
// schedule: one counted vmcnt + one barrier per K-tile; stage(t+2) inside
// compute(t). Waves 0-3 stage 3 loads/tile (A + 2xB), waves 4-7 stage 2
// (A + B) -> per-wave vmcnt(3)/vmcnt(2). Wave tile 64x48 (acc[4][3]).
// Epilogue branches per 16-wide fragment (192-wide tiles straddle the
// K/V column boundary at 2048, which is 16-aligned).
__global__ __launch_bounds__(512, 4) void k_gemm192(
    const unsigned short* __restrict__ A, const unsigned short* __restrict__ Bt,
    unsigned short* __restrict__ qkv, unsigned short* __restrict__ vt2) {
    constexpr int K = 1024, NT = K / 32;
    __shared__ unsigned short Abuf[3][4096];  // 24 KB: 128 rows paired -> 64x[2x32]
    __shared__ unsigned short Bbuf[3][6144];  // 36 KB: 192 rows paired -> 96x[2x32]
    const int tid = threadIdx.x;
    const int lane = tid & 63, wid = tid >> 6;
    const int wm = wid >> 2, wn = wid & 3;  // wave tile: rows wm*64, cols wn*48
    const int l4 = lane >> 4, l15 = lane & 15;
    const int m0 = blockIdx.y * 128, n0 = blockIdx.x * 192;

    // inverse-swizzled global coords for linear LDS staging
    int ar, ac;  // A load & B first-8KB load (same lb = tid*16)
    {
        const int lb = tid * 16;
        const int r2 = lb >> 7;
        const int w = (lb & 127) ^ ((r2 & 7) << 4);
        ar = r2 * 2 + (w >> 6);
        ac = (w & 63) >> 1;
    }
    int br1, bc1;  // B last-4KB load (tid < 256 only), lb = 8192 + tid*16
    {
        const int lb = 8192 + tid * 16;
        const int r2 = lb >> 7;
        const int w = (lb & 127) ^ ((r2 & 7) << 4);
        br1 = r2 * 2 + (w >> 6);
        bc1 = (w & 63) >> 1;
    }

    f32x4 acc[4][3] = {};

    auto STAGE = [&](int t, int d) {
        gload16(A + (size_t)(m0 + ar) * K + t * 32 + ac, &Abuf[d][tid * 8]);
        gload16(Bt + (size_t)(n0 + ar) * K + t * 32 + ac, &Bbuf[d][tid * 8]);
        if (wid < 4)
            gload16(Bt + (size_t)(n0 + br1) * K + t * 32 + bc1,
                    &Bbuf[d][4096 + tid * 8]);
    };

    auto rd = [&](const unsigned short* base, int R) {  // row R, col l4*8
        int byte = (R >> 1) * 128 + (R & 1) * 64 + l4 * 16;
        byte ^= ((R >> 1) & 7) << 4;
        return (const unsigned short*)((const char*)base + byte);
    };

    STAGE(0, 0);
    STAGE(1, 1);
    int d = 0;  // current buffer = t % 3
    for (int t = 0; t < NT; ++t) {
        if (t == NT - 1) {
            asm volatile("s_waitcnt vmcnt(0)" ::: "memory");
        } else if (wid < 4) {
            asm volatile("s_waitcnt vmcnt(3)" ::: "memory");
        } else {
            asm volatile("s_waitcnt vmcnt(2)" ::: "memory");
        }
        SB();
        __builtin_amdgcn_s_barrier();
        SB();
        const int dn = (d + 2 >= 3) ? d - 1 : d + 2;  // (t+2) % 3
        if (t + 2 < NT) STAGE(t + 2, dn);
        SB();
        bf16x8 af[4], bfr[3];
#pragma unroll
        for (int m = 0; m < 4; ++m)
            af[m] = ld_b8(rd(&Abuf[d][0], wm * 64 + m * 16 + l15));
#pragma unroll
        for (int n = 0; n < 3; ++n)
            bfr[n] = ld_b8(rd(&Bbuf[d][0], wn * 48 + n * 16 + l15));
        __builtin_amdgcn_s_setprio(1);
#pragma unroll
        for (int m = 0; m < 4; ++m)
#pragma unroll
            for (int n = 0; n < 3; ++n)
                acc[m][n] = MFMA16(af[m], bfr[n], acc[m][n]);
        __builtin_amdgcn_s_setprio(0);
        d = (d + 1 == 3) ? 0 : d + 1;
    }

    const int crow0 = m0 + wm * 64 + l4 * 4;  // multiple of 4
    const int ccol0 = n0 + wn * 48 + l15;
#pragma unroll
    for (int m = 0; m < 4; ++m)
#pragma unroll
        for (int n = 0; n < 3; ++n) {
            const int row = crow0 + m * 16;
            const int c = ccol0 + n * 16;
            if (c - l15 >= 2048) {  // V fragment -> vt2[bh][t/4][dh][4]
                const int cv = c - 2048;
                const int b = row >> 11, tt = row & 2047;
                const int h = cv >> 6, dh = cv & 63;
                ushort4 o;
                o.x = f2b(acc[m][n][0]);
                o.y = f2b(acc[m][n][1]);
                o.z = f2b(acc[m][n][2]);
                o.w = f2b(acc[m][n][3]);
                *(ushort4*)(vt2 + (size_t)(b * 16 + h) * 131072 + (tt >> 2) * 256 +
                            dh * 4) = o;
            } else {  // Q/K fragment -> qkv
#pragma unroll
                for (int r = 0; r < 4; ++r)
                    qkv[(size_t)(row + r) * 3072 + c] = f2b(acc[m][n][r]);
            }
        }
}

// ---------------- 256x128 BK=64 8-wave GEMM (gemm2: ao @ woutT -> f32) -----
__global__ __launch_bounds__(512, 2) void k_gemm256(
    const unsigned short* __restrict__ A, const unsigned short* __restrict__ Bt,
    float* __restrict__ Cv) {
    constexpr int K = 1024, NT = K / 64, NCOLS = 1024;
    __shared__ unsigned short Abuf[3][2][8192];
    __shared__ unsigned short Bbuf[3][8192];
    const int tid = threadIdx.x;
    const int lane = tid & 63, wid = tid >> 6;
    const int wr = wid >> 1, wc = wid & 1;
    const int l4 = lane >> 4, l15 = lane & 15;
    const int m0 = blockIdx.y * 256, n0 = blockIdx.x * 128;

    const int se0 = tid * 8, se1 = tid * 8 + 4096;
    const int r0_ = se0 >> 6, c0_ = (se0 & 63) ^ ((r0_ & 7) << 3);
    const int r1_ = se1 >> 6, c1_ = (se1 & 63) ^ ((r1_ & 7) << 3);

    f32x4 acc[4][4] = {};

    auto STAGE1 = [&](int t, int d) {
        const unsigned short* as = A + (size_t)m0 * K + t * 64;
        gload16(as + (size_t)r0_ * K + c0_, &Abuf[d][0][se0]);
        gload16(as + (size_t)r1_ * K + c1_, &Abuf[d][0][se1]);
        const unsigned short* bs = Bt + (size_t)n0 * K + t * 64;
        gload16(bs + (size_t)r0_ * K + c0_, &Bbuf[d][se0]);
    };
    auto STAGE2 = [&](int t, int d) {
        const unsigned short* as = A + (size_t)(m0 + 128) * K + t * 64;
        gload16(as + (size_t)r0_ * K + c0_, &Abuf[d][1][se0]);
        gload16(as + (size_t)r1_ * K + c1_, &Abuf[d][1][se1]);
        const unsigned short* bs = Bt + (size_t)n0 * K + t * 64;
        gload16(bs + (size_t)r1_ * K + c1_, &Bbuf[d][se1]);
    };

    auto swz = [](const unsigned short* base, int row, int col) {
        int byte = row * 128 + col * 2;
        byte ^= (row & 7) << 4;
        return (const unsigned short*)((const char*)base + byte);
    };

    STAGE1(0, 0);
    STAGE2(0, 0);
    STAGE1(1, 1);
    STAGE2(1, 1);
    int d = 0;
    for (int t = 0; t < NT; ++t) {
        if (t == NT - 1)
            asm volatile("s_waitcnt vmcnt(0)" ::: "memory");
        else
            asm volatile("s_waitcnt vmcnt(6)" ::: "memory");
        SB();
        __builtin_amdgcn_s_barrier();
        SB();
        const int dn = (d + 2 >= 3) ? d - 1 : d + 2;
        if (t + 2 < NT) STAGE1(t + 2, dn);
        SB();
        const unsigned short* Ah = &Abuf[d][wr >> 1][0];
        const unsigned short* Bh = &Bbuf[d][0];
        bf16x8 af[2][4], bfr[2][4];
#pragma unroll
        for (int ks = 0; ks < 2; ++ks) {
#pragma unroll
            for (int m = 0; m < 4; ++m)
                af[ks][m] =
                    ld_b8(swz(Ah, (wr & 1) * 64 + m * 16 + l15, ks * 32 + l4 * 8));
#pragma unroll
            for (int n = 0; n < 4; ++n)
                bfr[ks][n] = ld_b8(swz(Bh, wc * 64 + n * 16 + l15, ks * 32 + l4 * 8));
        }
        __builtin_amdgcn_s_setprio(1);
#pragma unroll
        for (int m = 0; m < 4; ++m)
#pragma unroll
            for (int n = 0; n < 4; ++n)
                acc[m][n] = MFMA16(af[0][m], bfr[0][n], acc[m][n]);
        __builtin_amdgcn_s_setprio(0);
        SB();
        if (t + 2 < NT) STAGE2(t + 2, dn);
        SB();
        __builtin_amdgcn_s_setprio(1);
#pragma unroll
        for (int m = 0; m < 4; ++m)
#pragma unroll
            for (int n = 0; n < 4; ++n)
                acc[m][n] = MFMA16(af[1][m], bfr[1][n], acc[m][n]);
        __builtin_amdgcn_s_setprio(0);
        d = (d + 1 == 3) ? 0 : d + 1;
    }

    const int crow0 = m0 + wr * 64 + l4 * 4;
    const int ccol0 = n0 + wc * 64 + l15;
#pragma unroll
    for (int m = 0; m < 4; ++m)
#pragma unroll
        for (int n = 0; n < 4; ++n)
#pragma unroll
            for (int r = 0; r < 4; ++r)
                Cv[(size_t)(crow0 + m * 16 + r) * NCOLS + ccol0 + n * 16] =
                    acc[m][n][r];
}

// ---------------- causal flash attention (proven 8-wave version) -----------
__global__ __launch_bounds__(512) void k_attn(const unsigned short* __restrict__ qkv,
                                              const unsigned short* __restrict__ vt2,
                                              unsigned short* __restrict__ ao) {
    __shared__ unsigned short Ks[2 * 4096];
    __shared__ unsigned short Vs[2 * 4096];
    const int bh = blockIdx.x & 63;
    const int p = blockIdx.x >> 6;  // 0..7
    const int b = bh >> 4, h = bh & 15;
    const int tid = threadIdx.x, lane = tid & 63, w = tid >> 6;  // w = 0..7
    const int l4 = lane >> 4, l15 = lane & 15;
    const int wrow = w * 16 + l15;

    const int sr0 = w * 8 + (lane >> 3);
    const int scol = 8 * ((lane & 7) ^ (lane >> 3));
    const unsigned short* Kg = qkv + (size_t)(b * T_) * 3072 + 1024 + h * 64;

    const unsigned short* Vg = vt2 + (size_t)bh * 131072;
    const int sv = w * 2 + (lane >> 5);
    const unsigned short* vsrcw =
        Vg + (4 * (sv & 3) + (sv >> 2)) * 256 + (lane & 31) * 8;

    const u32x4 onesw = {0x3f803f80u, 0x3f803f80u, 0x3f803f80u, 0x3f803f80u};
    const bf16x8 ones = __builtin_bit_cast(bf16x8, onesw);

    for (int half = 0; half < 2; ++half) {
        const int qq = half ? p : 15 - p;  // heavy q-tile first

        const unsigned short* qb =
            qkv + (size_t)(b * T_ + qq * 128 + wrow) * 3072 + h * 64;
        bf16x8 qf0, qf1;
        {
            const bf16x8 r0 = ld_b8(qb + l4 * 8);
            const bf16x8 r1 = ld_b8(qb + 32 + l4 * 8);
#pragma unroll
            for (int j = 0; j < 8; ++j) {
                qf0[j] = (__bf16)((float)r0[j] * 0.18033688f);
                qf1[j] = (__bf16)((float)r1[j] * 0.18033688f);
            }
        }

        f32x4 o[4] = {};  // o[ni][r]: row q=l4*4+r, col dh=ni*16+l15
        f32x4 o_l = {};   // row-sums of P (same row layout)

        auto STAGE = [&](int kt, int bi) {
            gload16(Kg + (size_t)(kt * 64 + sr0) * 3072 + scol,
                    Ks + bi * 4096 + w * 512);
            gload16(vsrcw + (size_t)kt * 4096, Vs + bi * 4096 + w * 512);
        };

        auto COMPUTE = [&](int bi, int dk) {  // dk = kt - 2*qq; mask when >= 0
            const unsigned short* Kb = Ks + bi * 4096;
            const unsigned short* Vb = Vs + bi * 4096;
            float tv[4][4];
            __builtin_amdgcn_s_setprio(1);
#pragma unroll
            for (int i = 0; i < 4; ++i) {
                const int key = i * 16 + l15;
                const int sw = (key & 7) << 4;
                const bf16x8 kf0 = ld_b8(Kb + (key * 128 + ((l4 * 16) ^ sw)) / 2);
                const bf16x8 kf1 = ld_b8(Kb + (key * 128 + ((l4 * 16 + 64) ^ sw)) / 2);
                f32x4 sacc = {};
                sacc = MFMA16(kf0, qf0, sacc);
                sacc = MFMA16(kf1, qf1, sacc);
#pragma unroll
                for (int r = 0; r < 4; ++r) tv[i][r] = sacc[r];
            }
            __builtin_amdgcn_s_setprio(0);
            if (dk >= 0) {
                const int base = dk * 64 - wrow;
#pragma unroll
                for (int i = 0; i < 4; ++i)
#pragma unroll
                    for (int r = 0; r < 4; ++r)
                        if (base + i * 16 + l4 * 4 + r > 0) tv[i][r] = -1e30f;
            }
            unsigned pw[8];  // pw[i*2+c]: P(keys i*16 + l4*4 + 2c, +2c+1), q=l15
#pragma unroll
            for (int i = 0; i < 4; ++i) {
                float pv[4];
#pragma unroll
                for (int r = 0; r < 4; ++r) pv[r] = __builtin_amdgcn_exp2f(tv[i][r]);
                pw[i * 2 + 0] = cvt_pk(pv[0], pv[1]);
                pw[i * 2 + 1] = cvt_pk(pv[2], pv[3]);
            }
            __builtin_amdgcn_s_setprio(1);
#pragma unroll
            for (int st = 0; st < 2; ++st) {
                const u32x4 pk = {pw[st * 4 + 0], pw[st * 4 + 1], pw[st * 4 + 2],
                                  pw[st * 4 + 3]};
                const bf16x8 pf = __builtin_bit_cast(bf16x8, pk);
                o_l = MFMA16(pf, ones, o_l);
#pragma unroll
                for (int ni = 0; ni < 4; ++ni) {
                    const unsigned short* vb =
                        Vb + (l4 * 4 + st * 2) * 256 + (ni * 16 + l15) * 4;
                    const u32x2 va = *(const u32x2*)vb;
                    const u32x2 vc = *(const u32x2*)(vb + 256);
                    const u32x4 vv = {va.x, va.y, vc.x, vc.y};
                    const bf16x8 vf = __builtin_bit_cast(bf16x8, vv);
                    o[ni] = MFMA16(pf, vf, o[ni]);
                }
            }
            __builtin_amdgcn_s_setprio(0);
        };

        const int NTI = 2 * qq + 1;  // last kv-tile index
        __syncthreads();             // protect LDS reuse across halves
        STAGE(0, 0);
        __syncthreads();
        for (int kt = 0; kt < NTI; ++kt) {
            STAGE(kt + 1, (kt + 1) & 1);
            COMPUTE(kt & 1, kt - 2 * qq);
            __syncthreads();
        }
        COMPUTE(NTI & 1, 1);

        unsigned short* aop =
            ao + (size_t)(b * T_ + qq * 128 + w * 16) * 1024 + h * 64;
#pragma unroll
        for (int r = 0; r < 4; ++r) {
            const float inv = 1.0f / o_l[r];
#pragma unroll
            for (int ni = 0; ni < 4; ++ni)
                aop[(size_t)(l4 * 4 + r) * 1024 + ni * 16 + l15] = f2b(o[ni][r] * inv);
        }
    }
}

extern "C" void kernel_launch(void* const* d_in, const int* in_sizes, int n_in,
                              void* d_out, int out_size, void* d_ws, size_t ws_size,
                              hipStream_t stream) {
    (void)in_sizes; (void)n_in; (void)out_size; (void)ws_size;
    const float* x = (const float*)d_in[0];
    const float* Wqkv = (const float*)d_in[1];
    const float* Wout = (const float*)d_in[2];
    char* ws = (char*)d_ws;
    unsigned short* xb = (unsigned short*)(ws + 0);             // 16 MB
    unsigned short* wqkvT = (unsigned short*)(ws + 16777216);   // 6 MB  (3072 x 1024)
    unsigned short* woutT = (unsigned short*)(ws + 23068672);   // 2 MB  (1024 x 1024)
    unsigned short* qkvb = (unsigned short*)(ws + 25165824);    // 48 MB (8192 x 3072, V third unused)
    unsigned short* vt2 = (unsigned short*)(ws + 75497472);     // 16 MB (64 x 512 x 64 x 4)
    unsigned short* ao = (unsigned short*)(ws + 92274688);      // 16 MB (8192 x 1024)

    k_prep<<<3072, 256, 0, stream>>>(x, Wqkv, Wout, xb, wqkvT, woutT);
    k_gemm192<<<dim3(16, 64), 512, 0, stream>>>(xb, wqkvT, qkvb, vt2);
    k_attn<<<512, 512, 0, stream>>>(qkvb, vt2, ao);
    k_gemm256<<<dim3(8, 32), 512, 0, stream>>>(ao, woutT, (float*)d_out);
}

// Round 19
// 143.198 us; speedup vs baseline: 1.0382x; 1.0382x over previous
//
#include <hip/hip_runtime.h>
#include <stdint.h>

#define T_ 2048
#define BB_ 4

typedef __bf16 bf16x8 __attribute__((ext_vector_type(8)));
typedef float f32x4 __attribute__((ext_vector_type(4)));
typedef unsigned short u16x8 __attribute__((ext_vector_type(8)));
typedef unsigned int u32x2 __attribute__((ext_vector_type(2)));
typedef unsigned int u32x4 __attribute__((ext_vector_type(4)));

__device__ __forceinline__ unsigned short f2b(float f) {
    unsigned int u = __builtin_bit_cast(unsigned int, f);
    return (unsigned short)((u + 0x7fffu + ((u >> 16) & 1u)) >> 16);
}

__device__ __forceinline__ unsigned cvt_pk(float lo, float hi) {
    unsigned r;
    asm("v_cvt_pk_bf16_f32 %0, %1, %2" : "=v"(r) : "v"(lo), "v"(hi));
    return r;
}

__device__ __forceinline__ void gload16(const void* g, const void* lds) {
    __builtin_amdgcn_global_load_lds(
        (__attribute__((address_space(1))) void*)(uintptr_t)g,
        (__attribute__((address_space(3))) void*)(uintptr_t)(unsigned int)(uintptr_t)lds,
        16, 0, 0);
}

__device__ __forceinline__ bf16x8 ld_b8(const unsigned short* p) {
    return *(const bf16x8*)p;
}

#define MFMA16(a, b, c) __builtin_amdgcn_mfma_f32_16x16x32_bf16((a), (b), (c), 0, 0, 0)
#define SB() __builtin_amdgcn_sched_barrier(0)

// ---------------- merged prep: x->bf16 + both weight transposes -----------
__device__ __forceinline__ void cvtT_body(const float* __restrict__ W,
                                          unsigned short* __restrict__ WT, int K,
                                          int N, int bid, int tid,
                                          unsigned short (*t_)[72]) {
    const int nt = bid % (N / 64), kt = bid / (N / 64);
    const int r = tid >> 2, c = (tid & 3) * 16;
    const float* src = W + (size_t)(kt * 64 + r) * N + nt * 64 + c;
#pragma unroll
    for (int j = 0; j < 16; j += 4) {
        float4 v = *(const float4*)(src + j);
        t_[r][c + j + 0] = f2b(v.x);
        t_[r][c + j + 1] = f2b(v.y);
        t_[r][c + j + 2] = f2b(v.z);
        t_[r][c + j + 3] = f2b(v.w);
    }
    __syncthreads();
    unsigned short* dst = WT + (size_t)(nt * 64 + r) * K + kt * 64 + c;
#pragma unroll
    for (int j = 0; j < 16; ++j) dst[j] = t_[c + j][r];
}

__global__ __launch_bounds__(256) void k_prep(
    const float* __restrict__ x, const float* __restrict__ Wqkv,
    const float* __restrict__ Wout, unsigned short* __restrict__ xb,
    unsigned short* __restrict__ wqkvT, unsigned short* __restrict__ woutT) {
    __shared__ unsigned short t_[64][72];
    const int bid = blockIdx.x, tid = threadIdx.x;
    if (bid < 768) {  // Wqkv (1024 x 3072) -> wqkvT (3072 x 1024)
        cvtT_body(Wqkv, wqkvT, 1024, 3072, bid, tid, t_);
    } else if (bid < 1024) {  // Wout (1024 x 1024) -> woutT
        cvtT_body(Wout, woutT, 1024, 1024, bid - 768, tid, t_);
    } else {  // x -> bf16, 2048 blocks, grid-stride
        int i = ((bid - 1024) * 256 + tid) * 4;
        const int stride = 2048 * 256 * 4;
        for (; i < BB_ * T_ * 1024; i += stride) {
            const float4 v = *(const float4*)(x + i);
            *(ushort4*)(xb + i) = make_ushort4(f2b(v.x), f2b(v.y), f2b(v.z), f2b(v.w));
        }
    }
}

// ---------------- 256x128 BK=32 8-wave GEMM, 3-buffer, 2 blocks/CU ---------
// Final proven config (rounds 15/17): LDS 72 KB -> 2 resident blocks.
// Paired-row layout: LDS row r2 holds global k-rows 2*r2, 2*r2+1 -> 128-B
// rows, XOR swizzle byte^=(r2&7)<<4, 0 bank conflicts. 3-buffer schedule:
// one counted vmcnt(3) + one barrier per K-tile; stage(t+2) inside
// compute(t). 864 TF = m97-class 2-barrier structural ceiling.
__global__ __launch_bounds__(512, 4) void k_gemm32(
    const unsigned short* __restrict__ A, const unsigned short* __restrict__ Bt,
    unsigned short* __restrict__ qkv, unsigned short* __restrict__ vt2) {
    constexpr int K = 1024, NT = K / 32;
    __shared__ unsigned short Abuf[3][8192];  // 48 KB
    __shared__ unsigned short Bbuf[3][4096];  // 24 KB
    const int tid = threadIdx.x;
    const int lane = tid & 63, wid = tid >> 6;
    const int wr = wid >> 1, wc = wid & 1;
    const int l4 = lane >> 4, l15 = lane & 15;
    const int m0 = blockIdx.y * 256, n0 = blockIdx.x * 128;

    int arow[2], acol[2];
#pragma unroll
    for (int c = 0; c < 2; ++c) {
        const int lb = c * 8192 + tid * 16;
        const int r2 = lb >> 7;
        const int w = (lb & 127) ^ ((r2 & 7) << 4);
        arow[c] = r2 * 2 + (w >> 6);
        acol[c] = (w & 63) >> 1;
    }
    int brow, bcol;
    {
        const int lb = tid * 16;
        const int r2 = lb >> 7;
        const int w = (lb & 127) ^ ((r2 & 7) << 4);
        brow = r2 * 2 + (w >> 6);
        bcol = (w & 63) >> 1;
    }

    f32x4 acc[4][4] = {};

    auto STAGE = [&](int t, int d) {
        gload16(A + (size_t)(m0 + arow[0]) * K + t * 32 + acol[0], &Abuf[d][tid * 8]);
        gload16(A + (size_t)(m0 + arow[1]) * K + t * 32 + acol[1],
                &Abuf[d][4096 + tid * 8]);
        gload16(Bt + (size_t)(n0 + brow) * K + t * 32 + bcol, &Bbuf[d][tid * 8]);
    };

    auto rd = [&](const unsigned short* base, int R) {  // row R, col l4*8
        int byte = (R >> 1) * 128 + (R & 1) * 64 + l4 * 16;
        byte ^= ((R >> 1) & 7) << 4;
        return (const unsigned short*)((const char*)base + byte);
    };

    STAGE(0, 0);
    STAGE(1, 1);
    int d = 0;  // current buffer = t % 3
    for (int t = 0; t < NT; ++t) {
        if (t == NT - 1)
            asm volatile("s_waitcnt vmcnt(0)" ::: "memory");
        else
            asm volatile("s_waitcnt vmcnt(3)" ::: "memory");
        SB();
        __builtin_amdgcn_s_barrier();
        SB();
        const int dn = (d + 2 >= 3) ? d - 1 : d + 2;  // (t+2) % 3
        if (t + 2 < NT) STAGE(t + 2, dn);
        SB();
        bf16x8 af[4], bfr[4];
#pragma unroll
        for (int m = 0; m < 4; ++m)
            af[m] = ld_b8(rd(&Abuf[d][0], wr * 64 + m * 16 + l15));
#pragma unroll
        for (int n = 0; n < 4; ++n)
            bfr[n] = ld_b8(rd(&Bbuf[d][0], wc * 64 + n * 16 + l15));
        __builtin_amdgcn_s_setprio(1);
#pragma unroll
        for (int m = 0; m < 4; ++m)
#pragma unroll
            for (int n = 0; n < 4; ++n)
                acc[m][n] = MFMA16(af[m], bfr[n], acc[m][n]);
        __builtin_amdgcn_s_setprio(0);
        d = (d + 1 == 3) ? 0 : d + 1;
    }

    const int crow0 = m0 + wr * 64 + l4 * 4;
    const int ccol0 = n0 + wc * 64 + l15;
    if (n0 >= 2048) {  // V third -> vt2[bh][t/4][dh][4]
#pragma unroll
        for (int m = 0; m < 4; ++m)
#pragma unroll
            for (int n = 0; n < 4; ++n) {
                const int row = crow0 + m * 16;
                const int c = ccol0 + n * 16 - 2048;
                const int b = row >> 11, tt = row & 2047;
                const int h = c >> 6, dh = c & 63;
                ushort4 o;
                o.x = f2b(acc[m][n][0]);
                o.y = f2b(acc[m][n][1]);
                o.z = f2b(acc[m][n][2]);
                o.w = f2b(acc[m][n][3]);
                *(ushort4*)(vt2 + (size_t)(b * 16 + h) * 131072 + (tt >> 2) * 256 +
                            dh * 4) = o;
            }
    } else {
#pragma unroll
        for (int m = 0; m < 4; ++m)
#pragma unroll
            for (int n = 0; n < 4; ++n)
#pragma unroll
                for (int r = 0; r < 4; ++r)
                    qkv[(size_t)(crow0 + m * 16 + r) * 3072 + ccol0 + n * 16] =
                        f2b(acc[m][n][r]);
    }
}

// ---------------- 256x128 BK=64 8-wave GEMM (gemm2: ao @ woutT -> f32) -----
__global__ __launch_bounds__(512, 2) void k_gemm256(
    const unsigned short* __restrict__ A, const unsigned short* __restrict__ Bt,
    float* __restrict__ Cv) {
    constexpr int K = 1024, NT = K / 64, NCOLS = 1024;
    __shared__ unsigned short Abuf[3][2][8192];
    __shared__ unsigned short Bbuf[3][8192];
    const int tid = threadIdx.x;
    const int lane = tid & 63, wid = tid >> 6;
    const int wr = wid >> 1, wc = wid & 1;
    const int l4 = lane >> 4, l15 = lane & 15;
    const int m0 = blockIdx.y * 256, n0 = blockIdx.x * 128;

    const int se0 = tid * 8, se1 = tid * 8 + 4096;
    const int r0_ = se0 >> 6, c0_ = (se0 & 63) ^ ((r0_ & 7) << 3);
    const int r1_ = se1 >> 6, c1_ = (se1 & 63) ^ ((r1_ & 7) << 3);

    f32x4 acc[4][4] = {};

    auto STAGE1 = [&](int t, int d) {
        const unsigned short* as = A + (size_t)m0 * K + t * 64;
        gload16(as + (size_t)r0_ * K + c0_, &Abuf[d][0][se0]);
        gload16(as + (size_t)r1_ * K + c1_, &Abuf[d][0][se1]);
        const unsigned short* bs = Bt + (size_t)n0 * K + t * 64;
        gload16(bs + (size_t)r0_ * K + c0_, &Bbuf[d][se0]);
    };
    auto STAGE2 = [&](int t, int d) {
        const unsigned short* as = A + (size_t)(m0 + 128) * K + t * 64;
        gload16(as + (size_t)r0_ * K + c0_, &Abuf[d][1][se0]);
        gload16(as + (size_t)r1_ * K + c1_, &Abuf[d][1][se1]);
        const unsigned short* bs = Bt + (size_t)n0 * K + t * 64;
        gload16(bs + (size_t)r1_ * K + c1_, &Bbuf[d][se1]);
    };

    auto swz = [](const unsigned short* base, int row, int col) {
        int byte = row * 128 + col * 2;
        byte ^= (row & 7) << 4;
        return (const unsigned short*)((const char*)base + byte);
    };

    STAGE1(0, 0);
    STAGE2(0, 0);
    STAGE1(1, 1);
    STAGE2(1, 1);
    int d = 0;
    for (int t = 0; t < NT; ++t) {
        if (t == NT - 1)
            asm volatile("s_waitcnt vmcnt(0)" ::: "memory");
        else
            asm volatile("s_waitcnt vmcnt(6)" ::: "memory");
        SB();
        __builtin_amdgcn_s_barrier();
        SB();
        const int dn = (d + 2 >= 3) ? d - 1 : d + 2;
        if (t + 2 < NT) STAGE1(t + 2, dn);
        SB();
        const unsigned short* Ah = &Abuf[d][wr >> 1][0];
        const unsigned short* Bh = &Bbuf[d][0];
        bf16x8 af[2][4], bfr[2][4];
#pragma unroll
        for (int ks = 0; ks < 2; ++ks) {
#pragma unroll
            for (int m = 0; m < 4; ++m)
                af[ks][m] =
                    ld_b8(swz(Ah, (wr & 1) * 64 + m * 16 + l15, ks * 32 + l4 * 8));
#pragma unroll
            for (int n = 0; n < 4; ++n)
                bfr[ks][n] = ld_b8(swz(Bh, wc * 64 + n * 16 + l15, ks * 32 + l4 * 8));
        }
        __builtin_amdgcn_s_setprio(1);
#pragma unroll
        for (int m = 0; m < 4; ++m)
#pragma unroll
            for (int n = 0; n < 4; ++n)
                acc[m][n] = MFMA16(af[0][m], bfr[0][n], acc[m][n]);
        __builtin_amdgcn_s_setprio(0);
        SB();
        if (t + 2 < NT) STAGE2(t + 2, dn);
        SB();
        __builtin_amdgcn_s_setprio(1);
#pragma unroll
        for (int m = 0; m < 4; ++m)
#pragma unroll
            for (int n = 0; n < 4; ++n)
                acc[m][n] = MFMA16(af[1][m], bfr[1][n], acc[m][n]);
        __builtin_amdgcn_s_setprio(0);
        d = (d + 1 == 3) ? 0 : d + 1;
    }

    const int crow0 = m0 + wr * 64 + l4 * 4;
    const int ccol0 = n0 + wc * 64 + l15;
#pragma unroll
    for (int m = 0; m < 4; ++m)
#pragma unroll
        for (int n = 0; n < 4; ++n)
#pragma unroll
            for (int r = 0; r < 4; ++r)
                Cv[(size_t)(crow0 + m * 16 + r) * NCOLS + ccol0 + n * 16] =
                    acc[m][n][r];
}

// ---------------- causal flash attention (proven 8-wave version) -----------
// 8 waves x 16 q-rows = 128 q-rows/block; K/V staged once for all 8 waves.
// q-tiles paired (15-p, p): 34 KV-tiles/block, grid = 512 (2/CU).
// Fixed-base softmax (P = exp2(t)) + l via ones-column MFMA; sigma-PV.
__global__ __launch_bounds__(512) void k_attn(const unsigned short* __restrict__ qkv,
                                              const unsigned short* __restrict__ vt2,
                                              unsigned short* __restrict__ ao) {
    __shared__ unsigned short Ks[2 * 4096];
    __shared__ unsigned short Vs[2 * 4096];
    const int bh = blockIdx.x & 63;
    const int p = blockIdx.x >> 6;  // 0..7
    const int b = bh >> 4, h = bh & 15;
    const int tid = threadIdx.x, lane = tid & 63, w = tid >> 6;  // w = 0..7
    const int l4 = lane >> 4, l15 = lane & 15;
    const int wrow = w * 16 + l15;

    const int sr0 = w * 8 + (lane >> 3);
    const int scol = 8 * ((lane & 7) ^ (lane >> 3));
    const unsigned short* Kg = qkv + (size_t)(b * T_) * 3072 + 1024 + h * 64;

    const unsigned short* Vg = vt2 + (size_t)bh * 131072;
    const int sv = w * 2 + (lane >> 5);
    const unsigned short* vsrcw =
        Vg + (4 * (sv & 3) + (sv >> 2)) * 256 + (lane & 31) * 8;

    const u32x4 onesw = {0x3f803f80u, 0x3f803f80u, 0x3f803f80u, 0x3f803f80u};
    const bf16x8 ones = __builtin_bit_cast(bf16x8, onesw);

    for (int half = 0; half < 2; ++half) {
        const int qq = half ? p : 15 - p;  // heavy q-tile first

        const unsigned short* qb =
            qkv + (size_t)(b * T_ + qq * 128 + wrow) * 3072 + h * 64;
        bf16x8 qf0, qf1;
        {
            const bf16x8 r0 = ld_b8(qb + l4 * 8);
            const bf16x8 r1 = ld_b8(qb + 32 + l4 * 8);
#pragma unroll
            for (int j = 0; j < 8; ++j) {
                qf0[j] = (__bf16)((float)r0[j] * 0.18033688f);
                qf1[j] = (__bf16)((float)r1[j] * 0.18033688f);
            }
        }

        f32x4 o[4] = {};  // o[ni][r]: row q=l4*4+r, col dh=ni*16+l15
        f32x4 o_l = {};   // row-sums of P (same row layout)

        auto STAGE = [&](int kt, int bi) {
            gload16(Kg + (size_t)(kt * 64 + sr0) * 3072 + scol,
                    Ks + bi * 4096 + w * 512);
            gload16(vsrcw + (size_t)kt * 4096, Vs + bi * 4096 + w * 512);
        };

        auto COMPUTE = [&](int bi, int dk) {  // dk = kt - 2*qq; mask when >= 0
            const unsigned short* Kb = Ks + bi * 4096;
            const unsigned short* Vb = Vs + bi * 4096;
            float tv[4][4];
            __builtin_amdgcn_s_setprio(1);
#pragma unroll
            for (int i = 0; i < 4; ++i) {
                const int key = i * 16 + l15;
                const int sw = (key & 7) << 4;
                const bf16x8 kf0 = ld_b8(Kb + (key * 128 + ((l4 * 16) ^ sw)) / 2);
                const bf16x8 kf1 = ld_b8(Kb + (key * 128 + ((l4 * 16 + 64) ^ sw)) / 2);
                f32x4 sacc = {};
                sacc = MFMA16(kf0, qf0, sacc);
                sacc = MFMA16(kf1, qf1, sacc);
#pragma unroll
                for (int r = 0; r < 4; ++r) tv[i][r] = sacc[r];
            }
            __builtin_amdgcn_s_setprio(0);
            if (dk >= 0) {
                const int base = dk * 64 - wrow;
#pragma unroll
                for (int i = 0; i < 4; ++i)
#pragma unroll
                    for (int r = 0; r < 4; ++r)
                        if (base + i * 16 + l4 * 4 + r > 0) tv[i][r] = -1e30f;
            }
            unsigned pw[8];  // pw[i*2+c]: P(keys i*16 + l4*4 + 2c, +2c+1), q=l15
#pragma unroll
            for (int i = 0; i < 4; ++i) {
                float pv[4];
#pragma unroll
                for (int r = 0; r < 4; ++r) pv[r] = __builtin_amdgcn_exp2f(tv[i][r]);
                pw[i * 2 + 0] = cvt_pk(pv[0], pv[1]);
                pw[i * 2 + 1] = cvt_pk(pv[2], pv[3]);
            }
            __builtin_amdgcn_s_setprio(1);
#pragma unroll
            for (int st = 0; st < 2; ++st) {
                const u32x4 pk = {pw[st * 4 + 0], pw[st * 4 + 1], pw[st * 4 + 2],
                                  pw[st * 4 + 3]};
                const bf16x8 pf = __builtin_bit_cast(bf16x8, pk);
                o_l = MFMA16(pf, ones, o_l);
#pragma unroll
                for (int ni = 0; ni < 4; ++ni) {
                    const unsigned short* vb =
                        Vb + (l4 * 4 + st * 2) * 256 + (ni * 16 + l15) * 4;
                    const u32x2 va = *(const u32x2*)vb;
                    const u32x2 vc = *(const u32x2*)(vb + 256);
                    const u32x4 vv = {va.x, va.y, vc.x, vc.y};
                    const bf16x8 vf = __builtin_bit_cast(bf16x8, vv);
                    o[ni] = MFMA16(pf, vf, o[ni]);
                }
            }
            __builtin_amdgcn_s_setprio(0);
        };

        const int NTI = 2 * qq + 1;  // last kv-tile index
        __syncthreads();             // protect LDS reuse across halves
        STAGE(0, 0);
        __syncthreads();
        for (int kt = 0; kt < NTI; ++kt) {
            STAGE(kt + 1, (kt + 1) & 1);
            COMPUTE(kt & 1, kt - 2 * qq);
            __syncthreads();
        }
        COMPUTE(NTI & 1, 1);

        unsigned short* aop =
            ao + (size_t)(b * T_ + qq * 128 + w * 16) * 1024 + h * 64;
#pragma unroll
        for (int r = 0; r < 4; ++r) {
            const float inv = 1.0f / o_l[r];
#pragma unroll
            for (int ni = 0; ni < 4; ++ni)
                aop[(size_t)(l4 * 4 + r) * 1024 + ni * 16 + l15] = f2b(o[ni][r] * inv);
        }
    }
}

extern "C" void kernel_launch(void* const* d_in, const int* in_sizes, int n_in,
                              void* d_out, int out_size, void* d_ws, size_t ws_size,
                              hipStream_t stream) {
    (void)in_sizes; (void)n_in; (void)out_size; (void)ws_size;
    const float* x = (const float*)d_in[0];
    const float* Wqkv = (const float*)d_in[1];
    const float* Wout = (const float*)d_in[2];
    char* ws = (char*)d_ws;
    unsigned short* xb = (unsigned short*)(ws + 0);             // 16 MB
    unsigned short* wqkvT = (unsigned short*)(ws + 16777216);   // 6 MB  (3072 x 1024)
    unsigned short* woutT = (unsigned short*)(ws + 23068672);   // 2 MB  (1024 x 1024)
    unsigned short* qkvb = (unsigned short*)(ws + 25165824);    // 48 MB (8192 x 3072, V third unused)
    unsigned short* vt2 = (unsigned short*)(ws + 75497472);     // 16 MB (64 x 512 x 64 x 4)
    unsigned short* ao = (unsigned short*)(ws + 92274688);      // 16 MB (8192 x 1024)

    k_prep<<<3072, 256, 0, stream>>>(x, Wqkv, Wout, xb, wqkvT, woutT);
    k_gemm32<<<dim3(24, 32), 512, 0, stream>>>(xb, wqkvT, qkvb, vt2);
    k_attn<<<512, 512, 0, stream>>>(qkvb, vt2, ao);
    k_gemm256<<<dim3(8, 32), 512, 0, stream>>>(ao, woutT, (float*)d_out);
}